// Round 16
// baseline (75.930 us; speedup 1.0000x reference)
//
#include <hip/hip_runtime.h>

#define NN 30000
#define NE 390000
#define HH 64
#define NGRAPH 64
#define AGG_BLOCKS 1280
#define NE_BLK 1524   // ceil(NE/256)
#define NN_BLK 118    // ceil(NN/256)

// ---------- sortable float encoding (ascending order preserved in uint) ----------
__device__ __forceinline__ unsigned sortable_f32(float f) {
    unsigned u = __float_as_uint(f);
    return (u & 0x80000000u) ? ~u : (u | 0x80000000u);
}

// tabs layout (float offsets):
// TV=0 (32x64), TC1=2048 (16x64), TC2=3072 (16x64), TC3=4096 (4x64),
// A=4352 (32x32), B=5376 (32x32), scratch: TQ=6400, TK=8448, TEK=10496
#define T_V   0
#define T_C1  2048
#define T_C2  3072
#define T_C3  4096
#define T_A   4352
#define T_B   5376
#define T_Q   6400
#define T_K   8448
#define T_EK  10496

// D1: esi (es only) + ns + cnt zero + nodeSel init + tab1   [fused, no memsets]
__global__ __launch_bounds__(256) void k_init(
        const int4* __restrict__ edge_states, const int4* __restrict__ node_states,
        const float* __restrict__ emb_sbv, const float* __restrict__ emb_sbr,
        const float* __restrict__ emb_edge, const float* __restrict__ emb_static,
        const float* __restrict__ Wq, const float* __restrict__ Wk,
        const float* __restrict__ Wv, const float* __restrict__ Wek,
        const float* __restrict__ Wc,
        unsigned char* __restrict__ esi, int* __restrict__ ns,
        unsigned* __restrict__ cnt, unsigned long long* __restrict__ nodeSel,
        float* __restrict__ tabs) {
    int b = blockIdx.x, t = threadIdx.x;
    if (b < NE_BLK) {
        int e = b * 256 + t;
        if (e < NE) {
            int4 v = edge_states[e];
            esi[e] = (unsigned char)(v.x + 2*v.y + 4*v.z + 8*v.w);
        }
    } else if (b < NE_BLK + NN_BLK) {
        int i = (b - NE_BLK) * 256 + t;
        if (i < NN) {
            int4 v = node_states[i];
            ns[i] = 2 * (v.x + 2*v.y + 4*v.z + 8*v.w);
            cnt[i] = 0u;
        }
    } else if (b < NE_BLK + NN_BLK + 41) {
        int idx = (b - NE_BLK - NN_BLK) * 256 + t;
        if (idx >= 10496) return;
        float acc = 0.f;
        if (idx < 2048) {              // TV
            int r = idx >> 6, h = idx & 63;
            for (int j = 0; j < 64; ++j) acc += emb_sbv[r*64+j] * Wv[h*64+j];
            tabs[T_V + idx] = acc;
        } else if (idx < 3072) {       // TC1
            int x = idx - 2048; int r = x >> 6, h = x & 63;
            for (int j = 0; j < 64; ++j) acc += emb_edge[r*64+j] * Wc[h*192+j];
            tabs[T_C1 + x] = acc;
        } else if (idx < 4096) {       // TC2
            int x = idx - 3072; int r = x >> 6, h = x & 63;
            for (int j = 0; j < 64; ++j) acc += emb_edge[r*64+j] * Wc[h*192+64+j];
            tabs[T_C2 + x] = acc;
        } else if (idx < 4352) {       // TC3
            int x = idx - 4096; int r = x >> 6, h = x & 63;
            for (int j = 0; j < 64; ++j) acc += emb_static[r*64+j] * Wc[h*192+128+j];
            tabs[T_C3 + x] = acc;
        } else if (idx < 6400) {       // TQ
            int x = idx - 4352; int r = x >> 6, h = x & 63;
            for (int j = 0; j < 64; ++j) acc += emb_sbv[r*64+j] * Wq[h*64+j];
            tabs[T_Q + x] = acc;
        } else if (idx < 8448) {       // TK
            int x = idx - 6400; int r = x >> 6, h = x & 63;
            for (int j = 0; j < 64; ++j) acc += emb_sbv[r*64+j] * Wk[h*64+j];
            tabs[T_K + x] = acc;
        } else {                       // TEK
            int x = idx - 8448; int r = x >> 6, h = x & 63;
            for (int j = 0; j < 64; ++j) acc += emb_sbr[r*64+j] * Wek[h*64+j];
            tabs[T_EK + x] = acc;
        }
    } else {
        // nodeSel init: 256 threads x 4 u64
        #pragma unroll
        for (int k = 0; k < 4; ++k) nodeSel[t * 4 + k] = ~0ull;
    }
}

// D2: rank histogram + node argmin + tab2
__global__ __launch_bounds__(256) void k_phase2(
        const int* __restrict__ ei1, unsigned* __restrict__ cnt,
        unsigned* __restrict__ rank, const int* __restrict__ ns,
        const int* __restrict__ batch_vec, const float* __restrict__ scalars,
        unsigned long long* __restrict__ nodeSel, float* __restrict__ tabs) {
    int b = blockIdx.x, t = threadIdx.x;
    if (b < NE_BLK) {
        int e = b * 256 + t;
        if (e < NE) rank[e] = atomicAdd(&cnt[ei1[e]], 1u);
    } else if (b < NE_BLK + NN_BLK) {
        int i = (b - NE_BLK) * 256 + t;
        if (i < NN) {
            int st = ns[i];
            int key = (st >> 1) * NGRAPH + batch_vec[i];
            unsigned long long pk = ((unsigned long long)sortable_f32(scalars[i]) << 32) | (unsigned)i;
            atomicMin(&nodeSel[key], pk);
        }
    } else {
        int idx = (b - NE_BLK - NN_BLK) * 256 + t;
        if (idx >= 2048) return;
        const float* TQ = tabs + T_Q;
        float acc = 0.f;
        if (idx < 1024) {
            int r1 = idx >> 5, r0 = idx & 31;
            const float* TK = tabs + T_K;
            for (int j = 0; j < 64; ++j) acc += TQ[r1*64+j] * TK[r0*64+j];
            tabs[T_A + idx] = acc * 0.125f;
        } else {
            int x = idx - 1024; int r1 = x >> 5, rk = x & 31;
            const float* TEK = tabs + T_EK;
            for (int j = 0; j < 64; ++j) acc += TQ[r1*64+j] * TEK[rk*64+j];
            tabs[T_B + x] = acc * 0.125f;
        }
    }
}

// D3: block sums of cnt + nodePk build {row, scalar-bits}
__global__ __launch_bounds__(256) void k_phase3(
        const unsigned* __restrict__ cnt, unsigned* __restrict__ bsum,
        const int* __restrict__ ns, const int* __restrict__ batch_vec,
        const unsigned long long* __restrict__ nodeSel,
        const float* __restrict__ scalars, uint2* __restrict__ nodePk) {
    int b = blockIdx.x, t = threadIdx.x;
    if (b < NN_BLK) {
        __shared__ unsigned red[256];
        int i = b * 256 + t;
        red[t] = (i < NN) ? cnt[i] : 0u;
        __syncthreads();
        for (int o = 128; o > 0; o >>= 1) {
            if (t < o) red[t] += red[t + o];
            __syncthreads();
        }
        if (t == 0) bsum[b] = red[0];
    } else {
        int i = (b - NN_BLK) * 256 + t;
        if (i < NN) {
            int st = ns[i];
            int key = (st >> 1) * NGRAPH + batch_vec[i];
            unsigned win = (unsigned)(nodeSel[key] & 0xffffffffull);
            unsigned row = (unsigned)st + (win == (unsigned)i ? 1u : 0u);
            nodePk[i] = make_uint2(row, __float_as_uint(scalars[i]));
        }
    }
}

// D4: per-block scan -> base, with the 118-element top-level scan INLINED
__global__ __launch_bounds__(256) void k_base(const unsigned* __restrict__ cnt,
        const unsigned* __restrict__ bsum, unsigned* __restrict__ base) {
    __shared__ unsigned sb[128];
    __shared__ unsigned s[256];
    int t = threadIdx.x;
    int b = blockIdx.x;
    if (t < 128) sb[t] = (t < NN_BLK) ? bsum[t] : 0u;
    __syncthreads();
    for (int o = 1; o < 128; o <<= 1) {
        unsigned u = 0u;
        if (t < 128 && t >= o) u = sb[t - o];
        __syncthreads();
        if (t < 128) sb[t] += u;          // inclusive scan of block sums
        __syncthreads();
    }
    unsigned P = (b == 0) ? 0u : sb[b - 1];
    int i = b * 256 + t;
    unsigned v = (i < NN) ? cnt[i] : 0u;
    s[t] = v;
    __syncthreads();
    for (int o = 1; o < 256; o <<= 1) {
        unsigned u = (t >= o) ? s[t - o] : 0u;
        __syncthreads();
        s[t] += u;
        __syncthreads();
    }
    if (i < NN) base[i] = P + s[t] - v;
    if (b == NN_BLK - 1 && t == 255) base[NN] = sb[NN_BLK - 1];
}

// D5: pack payload, scatter to CSR slot — no atomics
// key.x = e(19) | r0w(5)<<19 | es(4)<<24 | esr(4)<<28 ; key.y = sender-scalar bits
__global__ __launch_bounds__(256) void k_edge2(const int* __restrict__ ei0,
        const int* __restrict__ ei1, const uint2* __restrict__ nodePk,
        const unsigned char* __restrict__ esi, const int* __restrict__ rev_idx,
        const float* __restrict__ scalars, const unsigned* __restrict__ base,
        const unsigned* __restrict__ rank, uint2* __restrict__ sKey,
        float* __restrict__ sScal) {
    int e = blockIdx.x * 256 + threadIdx.x;
    if (e >= NE) return;
    int s0 = ei0[e], s1 = ei1[e];
    uint2 np = nodePk[s0];                        // {row, sender scalar}
    unsigned es = esi[e];
    unsigned esr = esi[rev_idx[e]];
    unsigned pos = base[s1] + rank[e];
    sKey[pos] = make_uint2((unsigned)e | (np.x << 19) | (es << 24) | (esr << 28), np.y);
    sScal[pos] = scalars[e];
}

// D6: one wave per node — in-wave argmin, softmax, si; quad-parallel messages.
// LDS trimmed to 29.7KB (emb_sbv node-base read via L2, 8KB hot) -> 5 blocks/CU.
__global__ __launch_bounds__(256) void k_agg(
        const unsigned* __restrict__ base, const uint2* __restrict__ sKey,
        const float* __restrict__ sScal, const uint2* __restrict__ nodePk,
        const float* __restrict__ tabs, const float* __restrict__ emb_edge,
        const float* __restrict__ emb_sbv, const int* __restrict__ step_ptr,
        float* __restrict__ out_node, float* __restrict__ out_edge) {
    // LDS: [0,6400) tabs (TV,TC1,TC2,TC3,A,B); [6400,7424) emb_edge
    __shared__ float lds[7424];
    __shared__ unsigned scr[4][32];   // per-wave argmin scratch: [16] min-sc, [16] min-e
    int tid = threadIdx.x;
    for (int j = tid; j < 6400; j += 256) lds[j] = tabs[j];
    for (int j = tid; j < 1024; j += 256) lds[6400 + j] = emb_edge[j];
    __syncthreads();
    int step = step_ptr[0];
    float invTau;
    if (step == -1) invTau = 1.0f;
    else { float frac = fminf((float)step / 10000.f, 1.f); invTau = 1.0f / (3.0f + (0.1f - 3.0f) * frac); }
    int wid = tid >> 6, lane = tid & 63;
    unsigned* mySc = scr[wid];
    unsigned* myE  = scr[wid] + 16;
    int q = lane >> 4, cidx = (lane & 15) << 2;
    for (int i = blockIdx.x * 4 + wid; i < NN; i += AGG_BLOCKS * 4) {
        unsigned j0 = base[i], j1 = base[i + 1];
        int d = (int)(j1 - j0);
        uint2 np = nodePk[i];
        int r1 = (int)np.x;
        float recv = __uint_as_float(np.y);
        const float* Arow = lds + T_A + r1 * 32;
        const float* Brow = lds + T_B + r1 * 32;
        float4 acc = {0.f, 0.f, 0.f, 0.f};
        if (lane < 16) { mySc[lane] = 0xffffffffu; myE[lane] = 0xffffffffu; }
        __builtin_amdgcn_sched_barrier(0);
        if (d > 0 && d <= 64) {
            // ---- register fast path ----
            bool act = lane < d;
            uint2 key = act ? sKey[j0 + lane] : make_uint2(0u, 0u);
            float sc  = act ? sScal[j0 + lane] : 0.f;
            unsigned scs = sortable_f32(sc);
            unsigned g = (key.x >> 20) & 15u;
            unsigned e19 = key.x & 0x7ffffu;
            if (act) atomicMin(&mySc[g], scs);
            __builtin_amdgcn_sched_barrier(0);
            unsigned ms = mySc[g];
            if (act && scs == ms) atomicMin(&myE[g], e19);
            __builtin_amdgcn_sched_barrier(0);
            bool win = act && (myE[g] == e19);
            int r0 = (key.x >> 19) & 31;
            int ekrow = (r0 & 30) + (win ? 1 : 0);
            float ex = act ? __expf((Arow[r0] + Brow[ekrow]) * invTau) : 0.f;
            float send = __uint_as_float(key.y);
            int si = (sc < recv ? 1 : 0) + (send + sc < recv ? 2 : 0);
            float s = ex;
            #pragma unroll
            for (int o = 1; o < 64; o <<= 1) s += __shfl_xor(s, o);
            float p = ex / s;
            int nIt = (d + 3) >> 2;
            for (int it = 0; it < nIt; ++it) {
                int jj = it * 4 + q;
                unsigned kx = __shfl(key.x, jj);
                int sii = __shfl(si, jj);
                float pp = __shfl(p, jj);
                if (jj < d) {
                    unsigned e = kx & 0x7ffffu;
                    int rr0 = (kx >> 19) & 31, es = (kx >> 24) & 15, esr = (kx >> 28) & 15;
                    float4 tv = *(const float4*)&lds[(rr0 << 6) + cidx];
                    float4 c1 = *(const float4*)&lds[T_C1 + (es << 6) + cidx];
                    float4 c2 = *(const float4*)&lds[T_C2 + (esr << 6) + cidx];
                    float4 c3 = *(const float4*)&lds[T_C3 + (sii << 6) + cidx];
                    float4 ee = *(const float4*)&lds[6400 + (es << 6) + cidx];
                    float4 o;
                    o.x = pp * (tv.x + c1.x + c2.x + c3.x);
                    o.y = pp * (tv.y + c1.y + c2.y + c3.y);
                    o.z = pp * (tv.z + c1.z + c2.z + c3.z);
                    o.w = pp * (tv.w + c1.w + c2.w + c3.w);
                    acc.x += o.x; acc.y += o.y; acc.z += o.z; acc.w += o.w;
                    o.x += ee.x; o.y += ee.y; o.z += ee.z; o.w += ee.w;
                    *(float4*)&out_edge[(size_t)e * 64 + cidx] = o;
                }
            }
        } else if (d > 64) {
            // ---- chunked general path ----
            for (unsigned c = j0; c < j1; c += 64) {
                unsigned j = c + lane;
                if (j < j1) {
                    uint2 key = sKey[j];
                    atomicMin(&mySc[(key.x >> 20) & 15u], sortable_f32(sScal[j]));
                }
            }
            __builtin_amdgcn_sched_barrier(0);
            for (unsigned c = j0; c < j1; c += 64) {
                unsigned j = c + lane;
                if (j < j1) {
                    uint2 key = sKey[j];
                    unsigned g = (key.x >> 20) & 15u;
                    if (sortable_f32(sScal[j]) == mySc[g]) atomicMin(&myE[g], key.x & 0x7ffffu);
                }
            }
            __builtin_amdgcn_sched_barrier(0);
            float s = 0.f;
            for (unsigned c = j0; c < j1; c += 64) {
                unsigned j = c + lane;
                if (j < j1) {
                    uint2 key = sKey[j];
                    bool win = (myE[(key.x >> 20) & 15u] == (key.x & 0x7ffffu));
                    int r0 = (key.x >> 19) & 31;
                    int ekrow = (r0 & 30) + (win ? 1 : 0);
                    s += __expf((Arow[r0] + Brow[ekrow]) * invTau);
                }
            }
            #pragma unroll
            for (int o = 1; o < 64; o <<= 1) s += __shfl_xor(s, o);
            float invS = 1.f / s;
            for (unsigned c = j0; c < j1; c += 4) {
                unsigned j = c + q;
                if (j < j1) {
                    uint2 key = sKey[j];
                    float sc = sScal[j];
                    bool win = (myE[(key.x >> 20) & 15u] == (key.x & 0x7ffffu));
                    int r0 = (key.x >> 19) & 31;
                    int ekrow = (r0 & 30) + (win ? 1 : 0);
                    float pp = __expf((Arow[r0] + Brow[ekrow]) * invTau) * invS;
                    float send = __uint_as_float(key.y);
                    int si = (sc < recv ? 1 : 0) + (send + sc < recv ? 2 : 0);
                    unsigned e = key.x & 0x7ffffu;
                    int es = (key.x >> 24) & 15, esr = (key.x >> 28) & 15;
                    float4 tv = *(const float4*)&lds[(r0 << 6) + cidx];
                    float4 c1 = *(const float4*)&lds[T_C1 + (es << 6) + cidx];
                    float4 c2 = *(const float4*)&lds[T_C2 + (esr << 6) + cidx];
                    float4 c3 = *(const float4*)&lds[T_C3 + (si << 6) + cidx];
                    float4 ee = *(const float4*)&lds[6400 + (es << 6) + cidx];
                    float4 o;
                    o.x = pp * (tv.x + c1.x + c2.x + c3.x);
                    o.y = pp * (tv.y + c1.y + c2.y + c3.y);
                    o.z = pp * (tv.z + c1.z + c2.z + c3.z);
                    o.w = pp * (tv.w + c1.w + c2.w + c3.w);
                    acc.x += o.x; acc.y += o.y; acc.z += o.z; acc.w += o.w;
                    o.x += ee.x; o.y += ee.y; o.z += ee.z; o.w += ee.w;
                    *(float4*)&out_edge[(size_t)e * 64 + cidx] = o;
                }
            }
        }
        // node reduce across quad groups and write (emb_sbv row via L2, 8KB hot)
        acc.x += __shfl_xor(acc.x, 16); acc.y += __shfl_xor(acc.y, 16);
        acc.z += __shfl_xor(acc.z, 16); acc.w += __shfl_xor(acc.w, 16);
        acc.x += __shfl_xor(acc.x, 32); acc.y += __shfl_xor(acc.y, 32);
        acc.z += __shfl_xor(acc.z, 32); acc.w += __shfl_xor(acc.w, 32);
        if (lane < 16) {
            float4 nb = *(const float4*)&emb_sbv[(r1 << 6) + cidx];
            float4 o;
            o.x = nb.x + acc.x; o.y = nb.y + acc.y; o.z = nb.z + acc.z; o.w = nb.w + acc.w;
            *(float4*)&out_node[(size_t)i * 64 + cidx] = o;
        }
    }
}

extern "C" void kernel_launch(void* const* d_in, const int* in_sizes, int n_in,
                              void* d_out, int out_size, void* d_ws, size_t ws_size,
                              hipStream_t stream) {
    const int4*  node_states = (const int4*)d_in[0];
    const int4*  edge_states = (const int4*)d_in[1];
    const float* scalars     = (const float*)d_in[2];
    const int*   edge_index  = (const int*)d_in[3];
    const int*   batch_vec   = (const int*)d_in[4];
    const int*   rev_idx     = (const int*)d_in[5];
    const float* emb_edge    = (const float*)d_in[6];
    const float* emb_sbv     = (const float*)d_in[7];
    const float* emb_sbr     = (const float*)d_in[8];
    const float* emb_static  = (const float*)d_in[9];
    const float* Wq  = (const float*)d_in[10];
    const float* Wk  = (const float*)d_in[11];
    const float* Wv  = (const float*)d_in[12];
    const float* Wek = (const float*)d_in[13];
    const float* Wc  = (const float*)d_in[15];
    const int*   step = (const int*)d_in[16];

    const int* ei0 = edge_index;
    const int* ei1 = edge_index + NE;

    char* ws = (char*)d_ws;
    // workspace layout (byte offsets, NON-OVERLAPPING):
    // [0,        120000)   ns i32 NN
    // [120000,   360000)   nodePk uint2 NN
    // [360000,   750016)   esi u8 NE (pad)
    // [750016,  2310016)   rank u32 NE
    // [2310016, 2430016)   cnt u32 NN
    // [2430080, 2550084)   base u32 NN+1
    // [2550144, 5670144)   sKey uint2 NE
    // [5670144, 7230144)   sScal f32 NE
    // [7230144, 7238336)   nodeSel u64 1024
    // [7238336, 7288512)   tabs f32 12544
    // [7288512, 7288984)   bsum u32 NN_BLK
    int*      ns     = (int*)(ws);
    uint2*    nodePk = (uint2*)(ws + 120000);
    unsigned char* esi = (unsigned char*)(ws + 360000);
    unsigned* rank   = (unsigned*)(ws + 750016);
    unsigned* cnt    = (unsigned*)(ws + 2310016);
    unsigned* baseA  = (unsigned*)(ws + 2430080);
    uint2*    sKey   = (uint2*)(ws + 2550144);
    float*    sScal  = (float*)(ws + 5670144);
    unsigned long long* nodeSel = (unsigned long long*)(ws + 7230144);
    float*    tabs   = (float*)(ws + 7238336);
    unsigned* bsum   = (unsigned*)(ws + 7288512);

    float* out_node = (float*)d_out;
    float* out_edge = out_node + (size_t)NN * HH;

    hipLaunchKernelGGL(k_init, dim3(NE_BLK + NN_BLK + 41 + 1), dim3(256), 0, stream,
                       edge_states, node_states, emb_sbv, emb_sbr, emb_edge, emb_static,
                       Wq, Wk, Wv, Wek, Wc, esi, ns, cnt, nodeSel, tabs);
    hipLaunchKernelGGL(k_phase2, dim3(NE_BLK + NN_BLK + 8), dim3(256), 0, stream,
                       ei1, cnt, rank, ns, batch_vec, scalars, nodeSel, tabs);
    hipLaunchKernelGGL(k_phase3, dim3(NN_BLK * 2), dim3(256), 0, stream,
                       cnt, bsum, ns, batch_vec, nodeSel, scalars, nodePk);
    hipLaunchKernelGGL(k_base, dim3(NN_BLK), dim3(256), 0, stream, cnt, bsum, baseA);
    hipLaunchKernelGGL(k_edge2, dim3(NE_BLK), dim3(256), 0, stream,
                       ei0, ei1, nodePk, esi, rev_idx, scalars, baseA, rank, sKey, sScal);
    hipLaunchKernelGGL(k_agg, dim3(AGG_BLOCKS), dim3(256), 0, stream,
                       baseA, sKey, sScal, nodePk, tabs, emb_edge, emb_sbv, step,
                       out_node, out_edge);
}

// Round 17
// 75.875 us; speedup vs baseline: 1.0007x; 1.0007x over previous
//
#include <hip/hip_runtime.h>

#define NN 30000
#define NE 390000
#define HH 64
#define NGRAPH 64
#define AGG_BLOCKS 1280
#define NE_BLK 1524   // ceil(NE/256)
#define NN_BLK 118    // ceil(NN/256)

// ---------- sortable float encoding (ascending order preserved in uint) ----------
__device__ __forceinline__ unsigned sortable_f32(float f) {
    unsigned u = __float_as_uint(f);
    return (u & 0x80000000u) ? ~u : (u | 0x80000000u);
}

// tabs layout (float offsets):
// TV=0 (32x64), TC1=2048 (16x64), TC2=3072 (16x64), TC3=4096 (4x64),
// A=4352 (32x32), B=5376 (32x32), scratch: TQ=6400, TK=8448, TEK=10496
#define T_V   0
#define T_C1  2048
#define T_C2  3072
#define T_C3  4096
#define T_A   4352
#define T_B   5376
#define T_Q   6400
#define T_K   8448
#define T_EK  10496

// D1: esi (es only) + ns + cnt zero + nodeSel init + tab1   [fused, no memsets]
__global__ __launch_bounds__(256) void k_init(
        const int4* __restrict__ edge_states, const int4* __restrict__ node_states,
        const float* __restrict__ emb_sbv, const float* __restrict__ emb_sbr,
        const float* __restrict__ emb_edge, const float* __restrict__ emb_static,
        const float* __restrict__ Wq, const float* __restrict__ Wk,
        const float* __restrict__ Wv, const float* __restrict__ Wek,
        const float* __restrict__ Wc,
        unsigned char* __restrict__ esi, int* __restrict__ ns,
        unsigned* __restrict__ cnt, unsigned long long* __restrict__ nodeSel,
        float* __restrict__ tabs) {
    int b = blockIdx.x, t = threadIdx.x;
    if (b < NE_BLK) {
        int e = b * 256 + t;
        if (e < NE) {
            int4 v = edge_states[e];
            esi[e] = (unsigned char)(v.x + 2*v.y + 4*v.z + 8*v.w);
        }
    } else if (b < NE_BLK + NN_BLK) {
        int i = (b - NE_BLK) * 256 + t;
        if (i < NN) {
            int4 v = node_states[i];
            ns[i] = 2 * (v.x + 2*v.y + 4*v.z + 8*v.w);
            cnt[i] = 0u;
        }
    } else if (b < NE_BLK + NN_BLK + 41) {
        int idx = (b - NE_BLK - NN_BLK) * 256 + t;
        if (idx >= 10496) return;
        float acc = 0.f;
        if (idx < 2048) {              // TV
            int r = idx >> 6, h = idx & 63;
            for (int j = 0; j < 64; ++j) acc += emb_sbv[r*64+j] * Wv[h*64+j];
            tabs[T_V + idx] = acc;
        } else if (idx < 3072) {       // TC1
            int x = idx - 2048; int r = x >> 6, h = x & 63;
            for (int j = 0; j < 64; ++j) acc += emb_edge[r*64+j] * Wc[h*192+j];
            tabs[T_C1 + x] = acc;
        } else if (idx < 4096) {       // TC2
            int x = idx - 3072; int r = x >> 6, h = x & 63;
            for (int j = 0; j < 64; ++j) acc += emb_edge[r*64+j] * Wc[h*192+64+j];
            tabs[T_C2 + x] = acc;
        } else if (idx < 4352) {       // TC3
            int x = idx - 4096; int r = x >> 6, h = x & 63;
            for (int j = 0; j < 64; ++j) acc += emb_static[r*64+j] * Wc[h*192+128+j];
            tabs[T_C3 + x] = acc;
        } else if (idx < 6400) {       // TQ
            int x = idx - 4352; int r = x >> 6, h = x & 63;
            for (int j = 0; j < 64; ++j) acc += emb_sbv[r*64+j] * Wq[h*64+j];
            tabs[T_Q + x] = acc;
        } else if (idx < 8448) {       // TK
            int x = idx - 6400; int r = x >> 6, h = x & 63;
            for (int j = 0; j < 64; ++j) acc += emb_sbv[r*64+j] * Wk[h*64+j];
            tabs[T_K + x] = acc;
        } else {                       // TEK
            int x = idx - 8448; int r = x >> 6, h = x & 63;
            for (int j = 0; j < 64; ++j) acc += emb_sbr[r*64+j] * Wek[h*64+j];
            tabs[T_EK + x] = acc;
        }
    } else {
        // nodeSel init: 256 threads x 4 u64
        #pragma unroll
        for (int k = 0; k < 4; ++k) nodeSel[t * 4 + k] = ~0ull;
    }
}

// D2: rank histogram + node argmin + tab2
__global__ __launch_bounds__(256) void k_phase2(
        const int* __restrict__ ei1, unsigned* __restrict__ cnt,
        unsigned* __restrict__ rank, const int* __restrict__ ns,
        const int* __restrict__ batch_vec, const float* __restrict__ scalars,
        unsigned long long* __restrict__ nodeSel, float* __restrict__ tabs) {
    int b = blockIdx.x, t = threadIdx.x;
    if (b < NE_BLK) {
        int e = b * 256 + t;
        if (e < NE) rank[e] = atomicAdd(&cnt[ei1[e]], 1u);
    } else if (b < NE_BLK + NN_BLK) {
        int i = (b - NE_BLK) * 256 + t;
        if (i < NN) {
            int st = ns[i];
            int key = (st >> 1) * NGRAPH + batch_vec[i];
            unsigned long long pk = ((unsigned long long)sortable_f32(scalars[i]) << 32) | (unsigned)i;
            atomicMin(&nodeSel[key], pk);
        }
    } else {
        int idx = (b - NE_BLK - NN_BLK) * 256 + t;
        if (idx >= 2048) return;
        const float* TQ = tabs + T_Q;
        float acc = 0.f;
        if (idx < 1024) {
            int r1 = idx >> 5, r0 = idx & 31;
            const float* TK = tabs + T_K;
            for (int j = 0; j < 64; ++j) acc += TQ[r1*64+j] * TK[r0*64+j];
            tabs[T_A + idx] = acc * 0.125f;
        } else {
            int x = idx - 1024; int r1 = x >> 5, rk = x & 31;
            const float* TEK = tabs + T_EK;
            for (int j = 0; j < 64; ++j) acc += TQ[r1*64+j] * TEK[rk*64+j];
            tabs[T_B + x] = acc * 0.125f;
        }
    }
}

// D3: block sums of cnt + nodePk build {row, scalar-bits}
__global__ __launch_bounds__(256) void k_phase3(
        const unsigned* __restrict__ cnt, unsigned* __restrict__ bsum,
        const int* __restrict__ ns, const int* __restrict__ batch_vec,
        const unsigned long long* __restrict__ nodeSel,
        const float* __restrict__ scalars, uint2* __restrict__ nodePk) {
    int b = blockIdx.x, t = threadIdx.x;
    if (b < NN_BLK) {
        __shared__ unsigned red[256];
        int i = b * 256 + t;
        red[t] = (i < NN) ? cnt[i] : 0u;
        __syncthreads();
        for (int o = 128; o > 0; o >>= 1) {
            if (t < o) red[t] += red[t + o];
            __syncthreads();
        }
        if (t == 0) bsum[b] = red[0];
    } else {
        int i = (b - NN_BLK) * 256 + t;
        if (i < NN) {
            int st = ns[i];
            int key = (st >> 1) * NGRAPH + batch_vec[i];
            unsigned win = (unsigned)(nodeSel[key] & 0xffffffffull);
            unsigned row = (unsigned)st + (win == (unsigned)i ? 1u : 0u);
            nodePk[i] = make_uint2(row, __float_as_uint(scalars[i]));
        }
    }
}

// D4: per-block scan -> base, with the 118-element top-level scan INLINED
__global__ __launch_bounds__(256) void k_base(const unsigned* __restrict__ cnt,
        const unsigned* __restrict__ bsum, unsigned* __restrict__ base) {
    __shared__ unsigned sb[128];
    __shared__ unsigned s[256];
    int t = threadIdx.x;
    int b = blockIdx.x;
    if (t < 128) sb[t] = (t < NN_BLK) ? bsum[t] : 0u;
    __syncthreads();
    for (int o = 1; o < 128; o <<= 1) {
        unsigned u = 0u;
        if (t < 128 && t >= o) u = sb[t - o];
        __syncthreads();
        if (t < 128) sb[t] += u;          // inclusive scan of block sums
        __syncthreads();
    }
    unsigned P = (b == 0) ? 0u : sb[b - 1];
    int i = b * 256 + t;
    unsigned v = (i < NN) ? cnt[i] : 0u;
    s[t] = v;
    __syncthreads();
    for (int o = 1; o < 256; o <<= 1) {
        unsigned u = (t >= o) ? s[t - o] : 0u;
        __syncthreads();
        s[t] += u;
        __syncthreads();
    }
    if (i < NN) base[i] = P + s[t] - v;
    if (b == NN_BLK - 1 && t == 255) base[NN] = sb[NN_BLK - 1];
}

// D5: pack payload, scatter to CSR slot — no atomics
// key.x = e(19) | r0w(5)<<19 | es(4)<<24 | esr(4)<<28 ; key.y = sender-scalar bits
__global__ __launch_bounds__(256) void k_edge2(const int* __restrict__ ei0,
        const int* __restrict__ ei1, const uint2* __restrict__ nodePk,
        const unsigned char* __restrict__ esi, const int* __restrict__ rev_idx,
        const float* __restrict__ scalars, const unsigned* __restrict__ base,
        const unsigned* __restrict__ rank, uint2* __restrict__ sKey,
        float* __restrict__ sScal) {
    int e = blockIdx.x * 256 + threadIdx.x;
    if (e >= NE) return;
    int s0 = ei0[e], s1 = ei1[e];
    uint2 np = nodePk[s0];                        // {row, sender scalar}
    unsigned es = esi[e];
    unsigned esr = esi[rev_idx[e]];
    unsigned pos = base[s1] + rank[e];
    sKey[pos] = make_uint2((unsigned)e | (np.x << 19) | (es << 24) | (esr << 28), np.y);
    sScal[pos] = scalars[e];
}

// D6: one wave per node — in-wave argmin, softmax, si; quad-parallel messages.
// LDS trimmed to 29.7KB (emb_sbv node-base read via L2, 8KB hot) -> 5 blocks/CU.
__global__ __launch_bounds__(256) void k_agg(
        const unsigned* __restrict__ base, const uint2* __restrict__ sKey,
        const float* __restrict__ sScal, const uint2* __restrict__ nodePk,
        const float* __restrict__ tabs, const float* __restrict__ emb_edge,
        const float* __restrict__ emb_sbv, const int* __restrict__ step_ptr,
        float* __restrict__ out_node, float* __restrict__ out_edge) {
    // LDS: [0,6400) tabs (TV,TC1,TC2,TC3,A,B); [6400,7424) emb_edge
    __shared__ float lds[7424];
    __shared__ unsigned scr[4][32];   // per-wave argmin scratch: [16] min-sc, [16] min-e
    int tid = threadIdx.x;
    for (int j = tid; j < 6400; j += 256) lds[j] = tabs[j];
    for (int j = tid; j < 1024; j += 256) lds[6400 + j] = emb_edge[j];
    __syncthreads();
    int step = step_ptr[0];
    float invTau;
    if (step == -1) invTau = 1.0f;
    else { float frac = fminf((float)step / 10000.f, 1.f); invTau = 1.0f / (3.0f + (0.1f - 3.0f) * frac); }
    int wid = tid >> 6, lane = tid & 63;
    unsigned* mySc = scr[wid];
    unsigned* myE  = scr[wid] + 16;
    int q = lane >> 4, cidx = (lane & 15) << 2;
    for (int i = blockIdx.x * 4 + wid; i < NN; i += AGG_BLOCKS * 4) {
        unsigned j0 = base[i], j1 = base[i + 1];
        int d = (int)(j1 - j0);
        uint2 np = nodePk[i];
        int r1 = (int)np.x;
        float recv = __uint_as_float(np.y);
        const float* Arow = lds + T_A + r1 * 32;
        const float* Brow = lds + T_B + r1 * 32;
        float4 acc = {0.f, 0.f, 0.f, 0.f};
        if (lane < 16) { mySc[lane] = 0xffffffffu; myE[lane] = 0xffffffffu; }
        __builtin_amdgcn_sched_barrier(0);
        if (d > 0 && d <= 64) {
            // ---- register fast path ----
            bool act = lane < d;
            uint2 key = act ? sKey[j0 + lane] : make_uint2(0u, 0u);
            float sc  = act ? sScal[j0 + lane] : 0.f;
            unsigned scs = sortable_f32(sc);
            unsigned g = (key.x >> 20) & 15u;
            unsigned e19 = key.x & 0x7ffffu;
            if (act) atomicMin(&mySc[g], scs);
            __builtin_amdgcn_sched_barrier(0);
            unsigned ms = mySc[g];
            if (act && scs == ms) atomicMin(&myE[g], e19);
            __builtin_amdgcn_sched_barrier(0);
            bool win = act && (myE[g] == e19);
            int r0 = (key.x >> 19) & 31;
            int ekrow = (r0 & 30) + (win ? 1 : 0);
            float ex = act ? __expf((Arow[r0] + Brow[ekrow]) * invTau) : 0.f;
            float send = __uint_as_float(key.y);
            int si = (sc < recv ? 1 : 0) + (send + sc < recv ? 2 : 0);
            float s = ex;
            #pragma unroll
            for (int o = 1; o < 64; o <<= 1) s += __shfl_xor(s, o);
            float p = ex / s;
            int nIt = (d + 3) >> 2;
            for (int it = 0; it < nIt; ++it) {
                int jj = it * 4 + q;
                unsigned kx = __shfl(key.x, jj);
                int sii = __shfl(si, jj);
                float pp = __shfl(p, jj);
                if (jj < d) {
                    unsigned e = kx & 0x7ffffu;
                    int rr0 = (kx >> 19) & 31, es = (kx >> 24) & 15, esr = (kx >> 28) & 15;
                    float4 tv = *(const float4*)&lds[(rr0 << 6) + cidx];
                    float4 c1 = *(const float4*)&lds[T_C1 + (es << 6) + cidx];
                    float4 c2 = *(const float4*)&lds[T_C2 + (esr << 6) + cidx];
                    float4 c3 = *(const float4*)&lds[T_C3 + (sii << 6) + cidx];
                    float4 ee = *(const float4*)&lds[6400 + (es << 6) + cidx];
                    float4 o;
                    o.x = pp * (tv.x + c1.x + c2.x + c3.x);
                    o.y = pp * (tv.y + c1.y + c2.y + c3.y);
                    o.z = pp * (tv.z + c1.z + c2.z + c3.z);
                    o.w = pp * (tv.w + c1.w + c2.w + c3.w);
                    acc.x += o.x; acc.y += o.y; acc.z += o.z; acc.w += o.w;
                    o.x += ee.x; o.y += ee.y; o.z += ee.z; o.w += ee.w;
                    *(float4*)&out_edge[(size_t)e * 64 + cidx] = o;
                }
            }
        } else if (d > 64) {
            // ---- chunked general path ----
            for (unsigned c = j0; c < j1; c += 64) {
                unsigned j = c + lane;
                if (j < j1) {
                    uint2 key = sKey[j];
                    atomicMin(&mySc[(key.x >> 20) & 15u], sortable_f32(sScal[j]));
                }
            }
            __builtin_amdgcn_sched_barrier(0);
            for (unsigned c = j0; c < j1; c += 64) {
                unsigned j = c + lane;
                if (j < j1) {
                    uint2 key = sKey[j];
                    unsigned g = (key.x >> 20) & 15u;
                    if (sortable_f32(sScal[j]) == mySc[g]) atomicMin(&myE[g], key.x & 0x7ffffu);
                }
            }
            __builtin_amdgcn_sched_barrier(0);
            float s = 0.f;
            for (unsigned c = j0; c < j1; c += 64) {
                unsigned j = c + lane;
                if (j < j1) {
                    uint2 key = sKey[j];
                    bool win = (myE[(key.x >> 20) & 15u] == (key.x & 0x7ffffu));
                    int r0 = (key.x >> 19) & 31;
                    int ekrow = (r0 & 30) + (win ? 1 : 0);
                    s += __expf((Arow[r0] + Brow[ekrow]) * invTau);
                }
            }
            #pragma unroll
            for (int o = 1; o < 64; o <<= 1) s += __shfl_xor(s, o);
            float invS = 1.f / s;
            for (unsigned c = j0; c < j1; c += 4) {
                unsigned j = c + q;
                if (j < j1) {
                    uint2 key = sKey[j];
                    float sc = sScal[j];
                    bool win = (myE[(key.x >> 20) & 15u] == (key.x & 0x7ffffu));
                    int r0 = (key.x >> 19) & 31;
                    int ekrow = (r0 & 30) + (win ? 1 : 0);
                    float pp = __expf((Arow[r0] + Brow[ekrow]) * invTau) * invS;
                    float send = __uint_as_float(key.y);
                    int si = (sc < recv ? 1 : 0) + (send + sc < recv ? 2 : 0);
                    unsigned e = key.x & 0x7ffffu;
                    int es = (key.x >> 24) & 15, esr = (key.x >> 28) & 15;
                    float4 tv = *(const float4*)&lds[(r0 << 6) + cidx];
                    float4 c1 = *(const float4*)&lds[T_C1 + (es << 6) + cidx];
                    float4 c2 = *(const float4*)&lds[T_C2 + (esr << 6) + cidx];
                    float4 c3 = *(const float4*)&lds[T_C3 + (si << 6) + cidx];
                    float4 ee = *(const float4*)&lds[6400 + (es << 6) + cidx];
                    float4 o;
                    o.x = pp * (tv.x + c1.x + c2.x + c3.x);
                    o.y = pp * (tv.y + c1.y + c2.y + c3.y);
                    o.z = pp * (tv.z + c1.z + c2.z + c3.z);
                    o.w = pp * (tv.w + c1.w + c2.w + c3.w);
                    acc.x += o.x; acc.y += o.y; acc.z += o.z; acc.w += o.w;
                    o.x += ee.x; o.y += ee.y; o.z += ee.z; o.w += ee.w;
                    *(float4*)&out_edge[(size_t)e * 64 + cidx] = o;
                }
            }
        }
        // node reduce across quad groups and write (emb_sbv row via L2, 8KB hot)
        acc.x += __shfl_xor(acc.x, 16); acc.y += __shfl_xor(acc.y, 16);
        acc.z += __shfl_xor(acc.z, 16); acc.w += __shfl_xor(acc.w, 16);
        acc.x += __shfl_xor(acc.x, 32); acc.y += __shfl_xor(acc.y, 32);
        acc.z += __shfl_xor(acc.z, 32); acc.w += __shfl_xor(acc.w, 32);
        if (lane < 16) {
            float4 nb = *(const float4*)&emb_sbv[(r1 << 6) + cidx];
            float4 o;
            o.x = nb.x + acc.x; o.y = nb.y + acc.y; o.z = nb.z + acc.z; o.w = nb.w + acc.w;
            *(float4*)&out_node[(size_t)i * 64 + cidx] = o;
        }
    }
}

extern "C" void kernel_launch(void* const* d_in, const int* in_sizes, int n_in,
                              void* d_out, int out_size, void* d_ws, size_t ws_size,
                              hipStream_t stream) {
    const int4*  node_states = (const int4*)d_in[0];
    const int4*  edge_states = (const int4*)d_in[1];
    const float* scalars     = (const float*)d_in[2];
    const int*   edge_index  = (const int*)d_in[3];
    const int*   batch_vec   = (const int*)d_in[4];
    const int*   rev_idx     = (const int*)d_in[5];
    const float* emb_edge    = (const float*)d_in[6];
    const float* emb_sbv     = (const float*)d_in[7];
    const float* emb_sbr     = (const float*)d_in[8];
    const float* emb_static  = (const float*)d_in[9];
    const float* Wq  = (const float*)d_in[10];
    const float* Wk  = (const float*)d_in[11];
    const float* Wv  = (const float*)d_in[12];
    const float* Wek = (const float*)d_in[13];
    const float* Wc  = (const float*)d_in[15];
    const int*   step = (const int*)d_in[16];

    const int* ei0 = edge_index;
    const int* ei1 = edge_index + NE;

    char* ws = (char*)d_ws;
    // workspace layout (byte offsets, NON-OVERLAPPING):
    // [0,        120000)   ns i32 NN
    // [120000,   360000)   nodePk uint2 NN
    // [360000,   750016)   esi u8 NE (pad)
    // [750016,  2310016)   rank u32 NE
    // [2310016, 2430016)   cnt u32 NN
    // [2430080, 2550084)   base u32 NN+1
    // [2550144, 5670144)   sKey uint2 NE
    // [5670144, 7230144)   sScal f32 NE
    // [7230144, 7238336)   nodeSel u64 1024
    // [7238336, 7288512)   tabs f32 12544
    // [7288512, 7288984)   bsum u32 NN_BLK
    int*      ns     = (int*)(ws);
    uint2*    nodePk = (uint2*)(ws + 120000);
    unsigned char* esi = (unsigned char*)(ws + 360000);
    unsigned* rank   = (unsigned*)(ws + 750016);
    unsigned* cnt    = (unsigned*)(ws + 2310016);
    unsigned* baseA  = (unsigned*)(ws + 2430080);
    uint2*    sKey   = (uint2*)(ws + 2550144);
    float*    sScal  = (float*)(ws + 5670144);
    unsigned long long* nodeSel = (unsigned long long*)(ws + 7230144);
    float*    tabs   = (float*)(ws + 7238336);
    unsigned* bsum   = (unsigned*)(ws + 7288512);

    float* out_node = (float*)d_out;
    float* out_edge = out_node + (size_t)NN * HH;

    hipLaunchKernelGGL(k_init, dim3(NE_BLK + NN_BLK + 41 + 1), dim3(256), 0, stream,
                       edge_states, node_states, emb_sbv, emb_sbr, emb_edge, emb_static,
                       Wq, Wk, Wv, Wek, Wc, esi, ns, cnt, nodeSel, tabs);
    hipLaunchKernelGGL(k_phase2, dim3(NE_BLK + NN_BLK + 8), dim3(256), 0, stream,
                       ei1, cnt, rank, ns, batch_vec, scalars, nodeSel, tabs);
    hipLaunchKernelGGL(k_phase3, dim3(NN_BLK * 2), dim3(256), 0, stream,
                       cnt, bsum, ns, batch_vec, nodeSel, scalars, nodePk);
    hipLaunchKernelGGL(k_base, dim3(NN_BLK), dim3(256), 0, stream, cnt, bsum, baseA);
    hipLaunchKernelGGL(k_edge2, dim3(NE_BLK), dim3(256), 0, stream,
                       ei0, ei1, nodePk, esi, rev_idx, scalars, baseA, rank, sKey, sScal);
    hipLaunchKernelGGL(k_agg, dim3(AGG_BLOCKS), dim3(256), 0, stream,
                       baseA, sKey, sScal, nodePk, tabs, emb_edge, emb_sbv, step,
                       out_node, out_edge);
}

// Round 18
// 75.162 us; speedup vs baseline: 1.0102x; 1.0095x over previous
//
#include <hip/hip_runtime.h>

#define NN 30000
#define NE 390000
#define HH 64
#define NGRAPH 64
#define AGG_BLOCKS 1280
#define NE_BLK 1524   // ceil(NE/256)
#define NN_BLK 118    // ceil(NN/256)

// ---------- sortable float encoding (ascending order preserved in uint) ----------
__device__ __forceinline__ unsigned sortable_f32(float f) {
    unsigned u = __float_as_uint(f);
    return (u & 0x80000000u) ? ~u : (u | 0x80000000u);
}

// tabs layout (float offsets):
// TV=0 (32x64), TC1=2048 (16x64), TC2=3072 (16x64), TC3=4096 (4x64),
// A=4352 (32x32), B=5376 (32x32), scratch: TQ=6400, TK=8448, TEK=10496
#define T_V   0
#define T_C1  2048
#define T_C2  3072
#define T_C3  4096
#define T_A   4352
#define T_B   5376
#define T_Q   6400
#define T_K   8448
#define T_EK  10496

// D1: esi (es only) + ns + cnt zero + nodeSel init + tab1   [fused, no memsets]
__global__ __launch_bounds__(256) void k_init(
        const int4* __restrict__ edge_states, const int4* __restrict__ node_states,
        const float* __restrict__ emb_sbv, const float* __restrict__ emb_sbr,
        const float* __restrict__ emb_edge, const float* __restrict__ emb_static,
        const float* __restrict__ Wq, const float* __restrict__ Wk,
        const float* __restrict__ Wv, const float* __restrict__ Wek,
        const float* __restrict__ Wc,
        unsigned char* __restrict__ esi, int* __restrict__ ns,
        unsigned* __restrict__ cnt, unsigned long long* __restrict__ nodeSel,
        float* __restrict__ tabs) {
    int b = blockIdx.x, t = threadIdx.x;
    if (b < NE_BLK) {
        int e = b * 256 + t;
        if (e < NE) {
            int4 v = edge_states[e];
            esi[e] = (unsigned char)(v.x + 2*v.y + 4*v.z + 8*v.w);
        }
    } else if (b < NE_BLK + NN_BLK) {
        int i = (b - NE_BLK) * 256 + t;
        if (i < NN) {
            int4 v = node_states[i];
            ns[i] = 2 * (v.x + 2*v.y + 4*v.z + 8*v.w);
            cnt[i] = 0u;
        }
    } else if (b < NE_BLK + NN_BLK + 41) {
        int idx = (b - NE_BLK - NN_BLK) * 256 + t;
        if (idx >= 10496) return;
        float acc = 0.f;
        if (idx < 2048) {              // TV
            int r = idx >> 6, h = idx & 63;
            for (int j = 0; j < 64; ++j) acc += emb_sbv[r*64+j] * Wv[h*64+j];
            tabs[T_V + idx] = acc;
        } else if (idx < 3072) {       // TC1
            int x = idx - 2048; int r = x >> 6, h = x & 63;
            for (int j = 0; j < 64; ++j) acc += emb_edge[r*64+j] * Wc[h*192+j];
            tabs[T_C1 + x] = acc;
        } else if (idx < 4096) {       // TC2
            int x = idx - 3072; int r = x >> 6, h = x & 63;
            for (int j = 0; j < 64; ++j) acc += emb_edge[r*64+j] * Wc[h*192+64+j];
            tabs[T_C2 + x] = acc;
        } else if (idx < 4352) {       // TC3
            int x = idx - 4096; int r = x >> 6, h = x & 63;
            for (int j = 0; j < 64; ++j) acc += emb_static[r*64+j] * Wc[h*192+128+j];
            tabs[T_C3 + x] = acc;
        } else if (idx < 6400) {       // TQ
            int x = idx - 4352; int r = x >> 6, h = x & 63;
            for (int j = 0; j < 64; ++j) acc += emb_sbv[r*64+j] * Wq[h*64+j];
            tabs[T_Q + x] = acc;
        } else if (idx < 8448) {       // TK
            int x = idx - 6400; int r = x >> 6, h = x & 63;
            for (int j = 0; j < 64; ++j) acc += emb_sbv[r*64+j] * Wk[h*64+j];
            tabs[T_K + x] = acc;
        } else {                       // TEK
            int x = idx - 8448; int r = x >> 6, h = x & 63;
            for (int j = 0; j < 64; ++j) acc += emb_sbr[r*64+j] * Wek[h*64+j];
            tabs[T_EK + x] = acc;
        }
    } else {
        // nodeSel init: 256 threads x 4 u64
        #pragma unroll
        for (int k = 0; k < 4; ++k) nodeSel[t * 4 + k] = ~0ull;
    }
}

// D2: rank histogram + node argmin + tab2
__global__ __launch_bounds__(256) void k_phase2(
        const int* __restrict__ ei1, unsigned* __restrict__ cnt,
        unsigned* __restrict__ rank, const int* __restrict__ ns,
        const int* __restrict__ batch_vec, const float* __restrict__ scalars,
        unsigned long long* __restrict__ nodeSel, float* __restrict__ tabs) {
    int b = blockIdx.x, t = threadIdx.x;
    if (b < NE_BLK) {
        int e = b * 256 + t;
        if (e < NE) rank[e] = atomicAdd(&cnt[ei1[e]], 1u);
    } else if (b < NE_BLK + NN_BLK) {
        int i = (b - NE_BLK) * 256 + t;
        if (i < NN) {
            int st = ns[i];
            int key = (st >> 1) * NGRAPH + batch_vec[i];
            unsigned long long pk = ((unsigned long long)sortable_f32(scalars[i]) << 32) | (unsigned)i;
            atomicMin(&nodeSel[key], pk);
        }
    } else {
        int idx = (b - NE_BLK - NN_BLK) * 256 + t;
        if (idx >= 2048) return;
        const float* TQ = tabs + T_Q;
        float acc = 0.f;
        if (idx < 1024) {
            int r1 = idx >> 5, r0 = idx & 31;
            const float* TK = tabs + T_K;
            for (int j = 0; j < 64; ++j) acc += TQ[r1*64+j] * TK[r0*64+j];
            tabs[T_A + idx] = acc * 0.125f;
        } else {
            int x = idx - 1024; int r1 = x >> 5, rk = x & 31;
            const float* TEK = tabs + T_EK;
            for (int j = 0; j < 64; ++j) acc += TQ[r1*64+j] * TEK[rk*64+j];
            tabs[T_B + x] = acc * 0.125f;
        }
    }
}

// D3: block sums of cnt + nodePk build {row, scalar-bits}
__global__ __launch_bounds__(256) void k_phase3(
        const unsigned* __restrict__ cnt, unsigned* __restrict__ bsum,
        const int* __restrict__ ns, const int* __restrict__ batch_vec,
        const unsigned long long* __restrict__ nodeSel,
        const float* __restrict__ scalars, uint2* __restrict__ nodePk) {
    int b = blockIdx.x, t = threadIdx.x;
    if (b < NN_BLK) {
        __shared__ unsigned red[256];
        int i = b * 256 + t;
        red[t] = (i < NN) ? cnt[i] : 0u;
        __syncthreads();
        for (int o = 128; o > 0; o >>= 1) {
            if (t < o) red[t] += red[t + o];
            __syncthreads();
        }
        if (t == 0) bsum[b] = red[0];
    } else {
        int i = (b - NN_BLK) * 256 + t;
        if (i < NN) {
            int st = ns[i];
            int key = (st >> 1) * NGRAPH + batch_vec[i];
            unsigned win = (unsigned)(nodeSel[key] & 0xffffffffull);
            unsigned row = (unsigned)st + (win == (unsigned)i ? 1u : 0u);
            nodePk[i] = make_uint2(row, __float_as_uint(scalars[i]));
        }
    }
}

// D4: per-block scan -> base, with the 118-element top-level scan INLINED
__global__ __launch_bounds__(256) void k_base(const unsigned* __restrict__ cnt,
        const unsigned* __restrict__ bsum, unsigned* __restrict__ base) {
    __shared__ unsigned sb[128];
    __shared__ unsigned s[256];
    int t = threadIdx.x;
    int b = blockIdx.x;
    if (t < 128) sb[t] = (t < NN_BLK) ? bsum[t] : 0u;
    __syncthreads();
    for (int o = 1; o < 128; o <<= 1) {
        unsigned u = 0u;
        if (t < 128 && t >= o) u = sb[t - o];
        __syncthreads();
        if (t < 128) sb[t] += u;          // inclusive scan of block sums
        __syncthreads();
    }
    unsigned P = (b == 0) ? 0u : sb[b - 1];
    int i = b * 256 + t;
    unsigned v = (i < NN) ? cnt[i] : 0u;
    s[t] = v;
    __syncthreads();
    for (int o = 1; o < 256; o <<= 1) {
        unsigned u = (t >= o) ? s[t - o] : 0u;
        __syncthreads();
        s[t] += u;
        __syncthreads();
    }
    if (i < NN) base[i] = P + s[t] - v;
    if (b == NN_BLK - 1 && t == 255) base[NN] = sb[NN_BLK - 1];
}

// D5: pack payload, scatter to CSR slot — no atomics
// key.x = e(19) | r0w(5)<<19 | es(4)<<24 | esr(4)<<28 ; key.y = sender-scalar bits
__global__ __launch_bounds__(256) void k_edge2(const int* __restrict__ ei0,
        const int* __restrict__ ei1, const uint2* __restrict__ nodePk,
        const unsigned char* __restrict__ esi, const int* __restrict__ rev_idx,
        const float* __restrict__ scalars, const unsigned* __restrict__ base,
        const unsigned* __restrict__ rank, uint2* __restrict__ sKey,
        float* __restrict__ sScal) {
    int e = blockIdx.x * 256 + threadIdx.x;
    if (e >= NE) return;
    int s0 = ei0[e], s1 = ei1[e];
    uint2 np = nodePk[s0];                        // {row, sender scalar}
    unsigned es = esi[e];
    unsigned esr = esi[rev_idx[e]];
    unsigned pos = base[s1] + rank[e];
    sKey[pos] = make_uint2((unsigned)e | (np.x << 19) | (es << 24) | (esr << 28), np.y);
    sScal[pos] = scalars[e];
}

// D6: one wave per node — in-wave argmin, softmax, si; quad-parallel messages.
// LDS trimmed to 29.7KB (emb_sbv node-base read via L2, 8KB hot) -> 5 blocks/CU.
__global__ __launch_bounds__(256) void k_agg(
        const unsigned* __restrict__ base, const uint2* __restrict__ sKey,
        const float* __restrict__ sScal, const uint2* __restrict__ nodePk,
        const float* __restrict__ tabs, const float* __restrict__ emb_edge,
        const float* __restrict__ emb_sbv, const int* __restrict__ step_ptr,
        float* __restrict__ out_node, float* __restrict__ out_edge) {
    // LDS: [0,6400) tabs (TV,TC1,TC2,TC3,A,B); [6400,7424) emb_edge
    __shared__ float lds[7424];
    __shared__ unsigned scr[4][32];   // per-wave argmin scratch: [16] min-sc, [16] min-e
    int tid = threadIdx.x;
    for (int j = tid; j < 6400; j += 256) lds[j] = tabs[j];
    for (int j = tid; j < 1024; j += 256) lds[6400 + j] = emb_edge[j];
    __syncthreads();
    int step = step_ptr[0];
    float invTau;
    if (step == -1) invTau = 1.0f;
    else { float frac = fminf((float)step / 10000.f, 1.f); invTau = 1.0f / (3.0f + (0.1f - 3.0f) * frac); }
    int wid = tid >> 6, lane = tid & 63;
    unsigned* mySc = scr[wid];
    unsigned* myE  = scr[wid] + 16;
    int q = lane >> 4, cidx = (lane & 15) << 2;
    for (int i = blockIdx.x * 4 + wid; i < NN; i += AGG_BLOCKS * 4) {
        unsigned j0 = base[i], j1 = base[i + 1];
        int d = (int)(j1 - j0);
        uint2 np = nodePk[i];
        int r1 = (int)np.x;
        float recv = __uint_as_float(np.y);
        const float* Arow = lds + T_A + r1 * 32;
        const float* Brow = lds + T_B + r1 * 32;
        float4 acc = {0.f, 0.f, 0.f, 0.f};
        if (lane < 16) { mySc[lane] = 0xffffffffu; myE[lane] = 0xffffffffu; }
        __builtin_amdgcn_sched_barrier(0);
        if (d > 0 && d <= 64) {
            // ---- register fast path ----
            bool act = lane < d;
            uint2 key = act ? sKey[j0 + lane] : make_uint2(0u, 0u);
            float sc  = act ? sScal[j0 + lane] : 0.f;
            unsigned scs = sortable_f32(sc);
            unsigned g = (key.x >> 20) & 15u;
            unsigned e19 = key.x & 0x7ffffu;
            if (act) atomicMin(&mySc[g], scs);
            __builtin_amdgcn_sched_barrier(0);
            unsigned ms = mySc[g];
            if (act && scs == ms) atomicMin(&myE[g], e19);
            __builtin_amdgcn_sched_barrier(0);
            bool win = act && (myE[g] == e19);
            int r0 = (key.x >> 19) & 31;
            int ekrow = (r0 & 30) + (win ? 1 : 0);
            float ex = act ? __expf((Arow[r0] + Brow[ekrow]) * invTau) : 0.f;
            float send = __uint_as_float(key.y);
            int si = (sc < recv ? 1 : 0) + (send + sc < recv ? 2 : 0);
            float s = ex;
            #pragma unroll
            for (int o = 1; o < 64; o <<= 1) s += __shfl_xor(s, o);
            float p = ex / s;
            int nIt = (d + 3) >> 2;
            for (int it = 0; it < nIt; ++it) {
                int jj = it * 4 + q;
                unsigned kx = __shfl(key.x, jj);
                int sii = __shfl(si, jj);
                float pp = __shfl(p, jj);
                if (jj < d) {
                    unsigned e = kx & 0x7ffffu;
                    int rr0 = (kx >> 19) & 31, es = (kx >> 24) & 15, esr = (kx >> 28) & 15;
                    float4 tv = *(const float4*)&lds[(rr0 << 6) + cidx];
                    float4 c1 = *(const float4*)&lds[T_C1 + (es << 6) + cidx];
                    float4 c2 = *(const float4*)&lds[T_C2 + (esr << 6) + cidx];
                    float4 c3 = *(const float4*)&lds[T_C3 + (sii << 6) + cidx];
                    float4 ee = *(const float4*)&lds[6400 + (es << 6) + cidx];
                    float4 o;
                    o.x = pp * (tv.x + c1.x + c2.x + c3.x);
                    o.y = pp * (tv.y + c1.y + c2.y + c3.y);
                    o.z = pp * (tv.z + c1.z + c2.z + c3.z);
                    o.w = pp * (tv.w + c1.w + c2.w + c3.w);
                    acc.x += o.x; acc.y += o.y; acc.z += o.z; acc.w += o.w;
                    o.x += ee.x; o.y += ee.y; o.z += ee.z; o.w += ee.w;
                    *(float4*)&out_edge[(size_t)e * 64 + cidx] = o;
                }
            }
        } else if (d > 64) {
            // ---- chunked general path ----
            for (unsigned c = j0; c < j1; c += 64) {
                unsigned j = c + lane;
                if (j < j1) {
                    uint2 key = sKey[j];
                    atomicMin(&mySc[(key.x >> 20) & 15u], sortable_f32(sScal[j]));
                }
            }
            __builtin_amdgcn_sched_barrier(0);
            for (unsigned c = j0; c < j1; c += 64) {
                unsigned j = c + lane;
                if (j < j1) {
                    uint2 key = sKey[j];
                    unsigned g = (key.x >> 20) & 15u;
                    if (sortable_f32(sScal[j]) == mySc[g]) atomicMin(&myE[g], key.x & 0x7ffffu);
                }
            }
            __builtin_amdgcn_sched_barrier(0);
            float s = 0.f;
            for (unsigned c = j0; c < j1; c += 64) {
                unsigned j = c + lane;
                if (j < j1) {
                    uint2 key = sKey[j];
                    bool win = (myE[(key.x >> 20) & 15u] == (key.x & 0x7ffffu));
                    int r0 = (key.x >> 19) & 31;
                    int ekrow = (r0 & 30) + (win ? 1 : 0);
                    s += __expf((Arow[r0] + Brow[ekrow]) * invTau);
                }
            }
            #pragma unroll
            for (int o = 1; o < 64; o <<= 1) s += __shfl_xor(s, o);
            float invS = 1.f / s;
            for (unsigned c = j0; c < j1; c += 4) {
                unsigned j = c + q;
                if (j < j1) {
                    uint2 key = sKey[j];
                    float sc = sScal[j];
                    bool win = (myE[(key.x >> 20) & 15u] == (key.x & 0x7ffffu));
                    int r0 = (key.x >> 19) & 31;
                    int ekrow = (r0 & 30) + (win ? 1 : 0);
                    float pp = __expf((Arow[r0] + Brow[ekrow]) * invTau) * invS;
                    float send = __uint_as_float(key.y);
                    int si = (sc < recv ? 1 : 0) + (send + sc < recv ? 2 : 0);
                    unsigned e = key.x & 0x7ffffu;
                    int es = (key.x >> 24) & 15, esr = (key.x >> 28) & 15;
                    float4 tv = *(const float4*)&lds[(r0 << 6) + cidx];
                    float4 c1 = *(const float4*)&lds[T_C1 + (es << 6) + cidx];
                    float4 c2 = *(const float4*)&lds[T_C2 + (esr << 6) + cidx];
                    float4 c3 = *(const float4*)&lds[T_C3 + (si << 6) + cidx];
                    float4 ee = *(const float4*)&lds[6400 + (es << 6) + cidx];
                    float4 o;
                    o.x = pp * (tv.x + c1.x + c2.x + c3.x);
                    o.y = pp * (tv.y + c1.y + c2.y + c3.y);
                    o.z = pp * (tv.z + c1.z + c2.z + c3.z);
                    o.w = pp * (tv.w + c1.w + c2.w + c3.w);
                    acc.x += o.x; acc.y += o.y; acc.z += o.z; acc.w += o.w;
                    o.x += ee.x; o.y += ee.y; o.z += ee.z; o.w += ee.w;
                    *(float4*)&out_edge[(size_t)e * 64 + cidx] = o;
                }
            }
        }
        // node reduce across quad groups and write (emb_sbv row via L2, 8KB hot)
        acc.x += __shfl_xor(acc.x, 16); acc.y += __shfl_xor(acc.y, 16);
        acc.z += __shfl_xor(acc.z, 16); acc.w += __shfl_xor(acc.w, 16);
        acc.x += __shfl_xor(acc.x, 32); acc.y += __shfl_xor(acc.y, 32);
        acc.z += __shfl_xor(acc.z, 32); acc.w += __shfl_xor(acc.w, 32);
        if (lane < 16) {
            float4 nb = *(const float4*)&emb_sbv[(r1 << 6) + cidx];
            float4 o;
            o.x = nb.x + acc.x; o.y = nb.y + acc.y; o.z = nb.z + acc.z; o.w = nb.w + acc.w;
            *(float4*)&out_node[(size_t)i * 64 + cidx] = o;
        }
    }
}

extern "C" void kernel_launch(void* const* d_in, const int* in_sizes, int n_in,
                              void* d_out, int out_size, void* d_ws, size_t ws_size,
                              hipStream_t stream) {
    const int4*  node_states = (const int4*)d_in[0];
    const int4*  edge_states = (const int4*)d_in[1];
    const float* scalars     = (const float*)d_in[2];
    const int*   edge_index  = (const int*)d_in[3];
    const int*   batch_vec   = (const int*)d_in[4];
    const int*   rev_idx     = (const int*)d_in[5];
    const float* emb_edge    = (const float*)d_in[6];
    const float* emb_sbv     = (const float*)d_in[7];
    const float* emb_sbr     = (const float*)d_in[8];
    const float* emb_static  = (const float*)d_in[9];
    const float* Wq  = (const float*)d_in[10];
    const float* Wk  = (const float*)d_in[11];
    const float* Wv  = (const float*)d_in[12];
    const float* Wek = (const float*)d_in[13];
    const float* Wc  = (const float*)d_in[15];
    const int*   step = (const int*)d_in[16];

    const int* ei0 = edge_index;
    const int* ei1 = edge_index + NE;

    char* ws = (char*)d_ws;
    // workspace layout (byte offsets, NON-OVERLAPPING):
    // [0,        120000)   ns i32 NN
    // [120000,   360000)   nodePk uint2 NN
    // [360000,   750016)   esi u8 NE (pad)
    // [750016,  2310016)   rank u32 NE
    // [2310016, 2430016)   cnt u32 NN
    // [2430080, 2550084)   base u32 NN+1
    // [2550144, 5670144)   sKey uint2 NE
    // [5670144, 7230144)   sScal f32 NE
    // [7230144, 7238336)   nodeSel u64 1024
    // [7238336, 7288512)   tabs f32 12544
    // [7288512, 7288984)   bsum u32 NN_BLK
    int*      ns     = (int*)(ws);
    uint2*    nodePk = (uint2*)(ws + 120000);
    unsigned char* esi = (unsigned char*)(ws + 360000);
    unsigned* rank   = (unsigned*)(ws + 750016);
    unsigned* cnt    = (unsigned*)(ws + 2310016);
    unsigned* baseA  = (unsigned*)(ws + 2430080);
    uint2*    sKey   = (uint2*)(ws + 2550144);
    float*    sScal  = (float*)(ws + 5670144);
    unsigned long long* nodeSel = (unsigned long long*)(ws + 7230144);
    float*    tabs   = (float*)(ws + 7238336);
    unsigned* bsum   = (unsigned*)(ws + 7288512);

    float* out_node = (float*)d_out;
    float* out_edge = out_node + (size_t)NN * HH;

    hipLaunchKernelGGL(k_init, dim3(NE_BLK + NN_BLK + 41 + 1), dim3(256), 0, stream,
                       edge_states, node_states, emb_sbv, emb_sbr, emb_edge, emb_static,
                       Wq, Wk, Wv, Wek, Wc, esi, ns, cnt, nodeSel, tabs);
    hipLaunchKernelGGL(k_phase2, dim3(NE_BLK + NN_BLK + 8), dim3(256), 0, stream,
                       ei1, cnt, rank, ns, batch_vec, scalars, nodeSel, tabs);
    hipLaunchKernelGGL(k_phase3, dim3(NN_BLK * 2), dim3(256), 0, stream,
                       cnt, bsum, ns, batch_vec, nodeSel, scalars, nodePk);
    hipLaunchKernelGGL(k_base, dim3(NN_BLK), dim3(256), 0, stream, cnt, bsum, baseA);
    hipLaunchKernelGGL(k_edge2, dim3(NE_BLK), dim3(256), 0, stream,
                       ei0, ei1, nodePk, esi, rev_idx, scalars, baseA, rank, sKey, sScal);
    hipLaunchKernelGGL(k_agg, dim3(AGG_BLOCKS), dim3(256), 0, stream,
                       baseA, sKey, sScal, nodePk, tabs, emb_edge, emb_sbv, step,
                       out_node, out_edge);
}